// Round 1
// baseline (932.760 us; speedup 1.0000x reference)
//
#include <hip/hip_runtime.h>
#include <hip/hip_bf16.h>

#define BATCH   16
#define NPTS    4096
#define CIN     256
#define COUT    512
#define KNN     16
#define NOUT    1024
#define XOUT_ELEMS 8388608   // 16*1024*512
#define LDA     40           // padded LDS leading dim (bf16 elems) for 32-k tiles

typedef __attribute__((ext_vector_type(4))) float f32x4;
typedef __attribute__((ext_vector_type(8))) short bf16x8;

__device__ __forceinline__ unsigned short f2bf_rne(float f) {
    unsigned u = __float_as_uint(f);
    return (unsigned short)((u + 0x7FFFu + ((u >> 16) & 1u)) >> 16);
}
__device__ __forceinline__ float bf2f(unsigned short s) {
    return __uint_as_float(((unsigned)s) << 16);
}

// blocks 0..15: FPS (one block per batch, persistent ~300us)
// blocks 16..2063: bf16 MFMA GEMM + BN + ReLU -> h (bf16) in workspace
extern "C" __global__ void __launch_bounds__(256)
fused_fps_gemm(const float* __restrict__ x, const float* __restrict__ p,
               const float* __restrict__ W, const float* __restrict__ bias,
               const float* __restrict__ gamma, const float* __restrict__ beta,
               const float* __restrict__ rmean, const float* __restrict__ rvar,
               int* __restrict__ fid, unsigned short* __restrict__ h)
{
    extern __shared__ char smem[];
    const int t = threadIdx.x;

    if (blockIdx.x < BATCH) {
        // ---------------- FPS: exact replica of numpy f32 arithmetic ----------------
        const int b = blockIdx.x;
        float* lx = (float*)smem;          // [4096]
        float* ly = lx + NPTS;
        float* lz = ly + NPTS;
        unsigned long long* warr = (unsigned long long*)(lz + NPTS); // [2][4] dbuf

        const float* pb = p + (size_t)b * NPTS * 3;
        for (int l = t; l < NPTS * 3; l += 256) {
            float v = pb[l];
            int pi = l / 3;
            int c = l - pi * 3;
            if (c == 0) lx[pi] = v; else if (c == 1) ly[pi] = v; else lz[pi] = v;
        }
        __syncthreads();

        float px[16], py[16], pz[16], d[16];
#pragma unroll
        for (int j = 0; j < 16; ++j) {
            int pi = (j << 8) + t;         // strided: pidx = j*256 + t
            px[j] = lx[pi]; py[j] = ly[pi]; pz[j] = lz[pi];
            d[j] = 3.4028235e38f;          // min(inf, dist_to_p0) == d0 exactly
        }
        if (t == 0) fid[b * NOUT] = b * NPTS;   // idxs[0] = 0 (global row)

        const int lane = t & 63;
        const int wv   = t >> 6;
        int winner = 0;
        for (int i = 1; i < NOUT; ++i) {
            float wx = lx[winner], wy = ly[winner], wz = lz[winner]; // LDS broadcast
            float bestd = -1.0f;
            int   bestj = 0;
#pragma unroll
            for (int j = 0; j < 16; ++j) {
                // must match np: ((dx*dx + dy*dy) + dz*dz), RN, no FMA contraction
                float dx = __fsub_rn(px[j], wx);
                float dy = __fsub_rn(py[j], wy);
                float dz = __fsub_rn(pz[j], wz);
                float s  = __fadd_rn(__fadd_rn(__fmul_rn(dx, dx), __fmul_rn(dy, dy)),
                                     __fmul_rn(dz, dz));
                float nd = fminf(d[j], s);
                d[j] = nd;
                bool gt = nd > bestd;      // strict > keeps earliest (lowest pidx) on ties
                bestd = gt ? nd : bestd;
                bestj = gt ? j  : bestj;
            }
            int bpi = (bestj << 8) + t;
            // d>=0 so float bits are order-isomorphic as unsigned; low word breaks
            // ties toward the LOWEST point index (np.argmax first-occurrence).
            unsigned long long key = ((unsigned long long)__float_as_uint(bestd) << 32)
                                   | (unsigned)(NPTS - 1 - bpi);
#pragma unroll
            for (int off = 32; off > 0; off >>= 1) {
                unsigned long long o = __shfl_xor(key, off, 64);
                if (o > key) key = o;
            }
            unsigned long long* wrow = warr + ((i & 1) << 2);  // double-buffered: 1 barrier/iter
            if (lane == 0) wrow[wv] = key;
            __syncthreads();
            unsigned long long k0 = wrow[0], k1 = wrow[1], k2 = wrow[2], k3 = wrow[3];
            if (k1 > k0) k0 = k1;
            if (k3 > k2) k2 = k3;
            if (k2 > k0) k0 = k2;
            winner = NPTS - 1 - (int)(unsigned)(k0 & 0xffffffffull);
            if (t == 0) fid[b * NOUT + i] = b * NPTS + winner;
        }
    } else {
        // ---------------- GEMM: h = relu(BN(x @ W^T + b)), bf16 MFMA ----------------
        const int bid = blockIdx.x - BATCH;
        const int bm = bid >> 2;           // 512 M-tiles of 128
        const int bn = bid & 3;            // 4 N-tiles of 128
        short* As = (short*)smem;          // [128][LDA] bf16
        short* Bs = As + 128 * LDA;        // [128][LDA] bf16 (W is [n][k] = B^T, perfect)

        const int lane = t & 63;
        const int wv = t >> 6;
        const int wm = wv >> 1, wn = wv & 1;   // 2x2 waves, 64x64 each
        const int quad = lane >> 4, l16 = lane & 15;
        const int m0 = bm * 128, n0 = bn * 128;

        f32x4 acc[4][4];
        const f32x4 zero = {0.0f, 0.0f, 0.0f, 0.0f};
#pragma unroll
        for (int a = 0; a < 4; ++a)
#pragma unroll
            for (int bb = 0; bb < 4; ++bb) acc[a][bb] = zero;

        const int srow = t >> 3;           // 0..31
        const int scol = (t & 7) << 2;     // 0,4,...,28

        for (int ks = 0; ks < 8; ++ks) {   // K = 256 in steps of 32
            const int k0 = ks * 32;
            __syncthreads();
#pragma unroll
            for (int it = 0; it < 4; ++it) {
                int row = srow + it * 32;
                float4 va = *(const float4*)(x + (size_t)(m0 + row) * CIN + k0 + scol);
                short4 pa = make_short4((short)f2bf_rne(va.x), (short)f2bf_rne(va.y),
                                        (short)f2bf_rne(va.z), (short)f2bf_rne(va.w));
                *(short4*)(As + row * LDA + scol) = pa;
                float4 vb = *(const float4*)(W + (size_t)(n0 + row) * CIN + k0 + scol);
                short4 pb2 = make_short4((short)f2bf_rne(vb.x), (short)f2bf_rne(vb.y),
                                         (short)f2bf_rne(vb.z), (short)f2bf_rne(vb.w));
                *(short4*)(Bs + row * LDA + scol) = pb2;
            }
            __syncthreads();
            bf16x8 af[4], bfr[4];
#pragma unroll
            for (int tm = 0; tm < 4; ++tm)
                af[tm] = *(const bf16x8*)(As + (wm * 64 + tm * 16 + l16) * LDA + quad * 8);
#pragma unroll
            for (int tn = 0; tn < 4; ++tn)
                bfr[tn] = *(const bf16x8*)(Bs + (wn * 64 + tn * 16 + l16) * LDA + quad * 8);
#pragma unroll
            for (int tm = 0; tm < 4; ++tm)
#pragma unroll
                for (int tn = 0; tn < 4; ++tn)
                    acc[tm][tn] = __builtin_amdgcn_mfma_f32_16x16x32_bf16(
                        af[tm], bfr[tn], acc[tm][tn], 0, 0, 0);
        }
        // epilogue: fold bias+BN, relu, store bf16
#pragma unroll
        for (int tn = 0; tn < 4; ++tn) {
            int c = n0 + wn * 64 + tn * 16 + l16;
            float sc = gamma[c] / sqrtf(rvar[c] + 1e-5f);
            float sh = (bias[c] - rmean[c]) * sc + beta[c];
#pragma unroll
            for (int tm = 0; tm < 4; ++tm) {
                int rbase = m0 + wm * 64 + tm * 16 + quad * 4;
#pragma unroll
                for (int r = 0; r < 4; ++r) {
                    float v = fmaxf(acc[tm][tn][r] * sc + sh, 0.0f);
                    h[(size_t)(rbase + r) * COUT + c] = f2bf_rne(v);
                }
            }
        }
    }
}

// one block per sampled point: gather K=16 rows of h, max over K, + p_out copy
extern "C" __global__ void __launch_bounds__(128)
gather_maxpool(const int* __restrict__ sid32, const float* __restrict__ p,
               const int* __restrict__ fid, const unsigned short* __restrict__ h,
               float* __restrict__ out)
{
    const int j = blockIdx.x;     // 0..16383
    const int t = threadIdx.x;
    __shared__ int rows[KNN];
    const int frow = fid[j];
    // sid_euc may land as int32 or int64 depending on JAX x64 config; int64 high
    // words of nonneg values < 2^31 are all zero -> sniff.
    bool is64 = (sid32[1] == 0) && (sid32[3] == 0) && (sid32[5] == 0);
    if (t < KNN) {
        long long e = (long long)frow * KNN + t;
        rows[t] = is64 ? sid32[e * 2] : sid32[e];
    }
    if (t < 3) out[(size_t)XOUT_ELEMS + (size_t)j * 3 + t] = p[(size_t)frow * 3 + t];
    __syncthreads();

    const int c4 = t << 2;
    float m0 = -3.4028235e38f, m1 = m0, m2 = m0, m3 = m0;
#pragma unroll
    for (int k = 0; k < KNN; ++k) {
        const ushort4 v = *(const ushort4*)(h + (size_t)rows[k] * COUT + c4);
        m0 = fmaxf(m0, bf2f(v.x));
        m1 = fmaxf(m1, bf2f(v.y));
        m2 = fmaxf(m2, bf2f(v.z));
        m3 = fmaxf(m3, bf2f(v.w));
    }
    *(float4*)(out + (size_t)j * COUT + c4) = make_float4(m0, m1, m2, m3);
}

extern "C" void kernel_launch(void* const* d_in, const int* in_sizes, int n_in,
                              void* d_out, int out_size, void* d_ws, size_t ws_size,
                              hipStream_t stream)
{
    const float* x     = (const float*)d_in[0];
    const float* p     = (const float*)d_in[1];
    const int*   sid   = (const int*)d_in[2];   // tid_euc (d_in[3]) unused by reference
    const float* W     = (const float*)d_in[4];
    const float* bias  = (const float*)d_in[5];
    const float* gamma = (const float*)d_in[6];
    const float* beta  = (const float*)d_in[7];
    const float* rmean = (const float*)d_in[8];
    const float* rvar  = (const float*)d_in[9];
    float* out = (float*)d_out;

    int* fid = (int*)d_ws;                                   // 16384 int32
    unsigned short* h = (unsigned short*)((char*)d_ws + 65536); // 65536x512 bf16 (67MB)

    const size_t lds = 3 * NPTS * 4 + 2 * 4 * 8;             // 49216 B (FPS needs most)
    hipLaunchKernelGGL(fused_fps_gemm, dim3(BATCH + 512 * 4), dim3(256), lds, stream,
                       x, p, W, bias, gamma, beta, rmean, rvar, fid, h);
    hipLaunchKernelGGL(gather_maxpool, dim3(BATCH * NOUT), dim3(128), 0, stream,
                       sid, p, fid, h, out);
}

// Round 2
// 745.678 us; speedup vs baseline: 1.2509x; 1.2509x over previous
//
#include <hip/hip_runtime.h>
#include <hip/hip_bf16.h>

#define BATCH   16
#define NPTS    4096
#define CIN     256
#define COUT    512
#define KNN     16
#define NOUT    1024
#define XOUT_ELEMS 8388608   // 16*1024*512
#define LDA     40           // padded LDS leading dim (bf16 elems) for 32-k tiles

typedef __attribute__((ext_vector_type(4))) float f32x4;
typedef __attribute__((ext_vector_type(8))) short bf16x8;

__device__ __forceinline__ unsigned short f2bf_rne(float f) {
    unsigned u = __float_as_uint(f);
    return (unsigned short)((u + 0x7FFFu + ((u >> 16) & 1u)) >> 16);
}
__device__ __forceinline__ float bf2f(unsigned short s) {
    return __uint_as_float(((unsigned)s) << 16);
}

// 6-step DPP max-reduce: lane 63 ends with the wave max. Pure VALU (no DS ops).
// row_shr:1/2/4/8 then row_bcast15 (0x142), row_bcast31 (0x143). Invalid lanes
// return `old` (= own value) -> fmax(v,v), always safe.
__device__ __forceinline__ float wave_max_dpp(float v) {
    int x, y;
    x = __float_as_int(v);
    y = __builtin_amdgcn_update_dpp(x, x, 0x111, 0xf, 0xf, false);
    v = fmaxf(v, __int_as_float(y)); x = __float_as_int(v);
    y = __builtin_amdgcn_update_dpp(x, x, 0x112, 0xf, 0xf, false);
    v = fmaxf(v, __int_as_float(y)); x = __float_as_int(v);
    y = __builtin_amdgcn_update_dpp(x, x, 0x114, 0xf, 0xf, false);
    v = fmaxf(v, __int_as_float(y)); x = __float_as_int(v);
    y = __builtin_amdgcn_update_dpp(x, x, 0x118, 0xf, 0xf, false);
    v = fmaxf(v, __int_as_float(y)); x = __float_as_int(v);
    y = __builtin_amdgcn_update_dpp(x, x, 0x142, 0xf, 0xf, false);
    v = fmaxf(v, __int_as_float(y)); x = __float_as_int(v);
    y = __builtin_amdgcn_update_dpp(x, x, 0x143, 0xf, 0xf, false);
    v = fmaxf(v, __int_as_float(y));
    return v;   // valid in lane 63
}

// blocks 0..15: FPS (one block per batch, persistent tail)
// blocks 16..2063: bf16 MFMA GEMM + BN + ReLU -> h (bf16) in workspace
extern "C" __global__ void __launch_bounds__(256)
fused_fps_gemm(const float* __restrict__ x, const float* __restrict__ p,
               const float* __restrict__ W, const float* __restrict__ bias,
               const float* __restrict__ gamma, const float* __restrict__ beta,
               const float* __restrict__ rmean, const float* __restrict__ rvar,
               int* __restrict__ fid, unsigned short* __restrict__ h)
{
    extern __shared__ char smem[];
    const int t = threadIdx.x;

    if (blockIdx.x < BATCH) {
        // ---------------- FPS: exact replica of numpy f32 arithmetic ----------------
        const int b = blockIdx.x;
        float* lx = (float*)smem;          // [4096]
        float* ly = lx + NPTS;
        float* lz = ly + NPTS;
        unsigned long long* warr = (unsigned long long*)(lz + NPTS); // [2][4] dbuf

        const float* pb = p + (size_t)b * NPTS * 3;
        for (int l = t; l < NPTS * 3; l += 256) {
            float v = pb[l];
            int pi = l / 3;
            int c = l - pi * 3;
            if (c == 0) lx[pi] = v; else if (c == 1) ly[pi] = v; else lz[pi] = v;
        }
        __syncthreads();

        // contiguous ownership: thread t owns points [16t, 16t+16). This makes
        // lowest-lane == lowest-point-index, so ballot+ctz = np.argmax tie-break.
        float px[16], py[16], pz[16], d[16];
        const int base = t << 4;
#pragma unroll
        for (int j = 0; j < 16; ++j) {
            px[j] = lx[base + j]; py[j] = ly[base + j]; pz[j] = lz[base + j];
            d[j] = 3.4028235e38f;          // min(FLT_MAX, dist_to_p0) == d0 exactly
        }
        if (t == 0) fid[b * NOUT] = b * NPTS;   // idxs[0] = 0 (global row)

        int winner = 0;
        for (int i = 1; i < NOUT; ++i) {
            float wx = lx[winner], wy = ly[winner], wz = lz[winner]; // LDS broadcast
            float bestd = -1.0f;
            int   bestj = 0;
#pragma unroll
            for (int j = 0; j < 16; ++j) {
                // must match np: ((dx*dx + dy*dy) + dz*dz), RN, no FMA contraction
                float dx = __fsub_rn(px[j], wx);
                float dy = __fsub_rn(py[j], wy);
                float dz = __fsub_rn(pz[j], wz);
                float s  = __fadd_rn(__fadd_rn(__fmul_rn(dx, dx), __fmul_rn(dy, dy)),
                                     __fmul_rn(dz, dz));
                float nd = fminf(d[j], s);
                d[j] = nd;
                bool gt = nd > bestd;      // strict > keeps earliest (lowest j) on ties
                bestd = gt ? nd : bestd;
                bestj = gt ? j  : bestj;
            }
            // wave argmax: DPP value-max, then first lane achieving it (lowest
            // lane = lowest point index with contiguous ownership).
            float vmax = wave_max_dpp(bestd);
            float wmax = __int_as_float(
                __builtin_amdgcn_readlane(__float_as_int(vmax), 63));
            unsigned long long msk = __ballot(bestd == wmax);
            int lead = (int)__builtin_ctzll(msk);
            int wbpi = __builtin_amdgcn_readlane(base + bestj, lead);
            // dists >= 0 so f32 bits are order-isomorphic as unsigned; low word
            // breaks cross-wave ties toward the LOWEST point index.
            unsigned long long key = ((unsigned long long)__float_as_uint(wmax) << 32)
                                   | (unsigned)(NPTS - 1 - wbpi);
            unsigned long long* wrow = warr + ((i & 1) << 2);  // dbuf: 1 barrier/iter
            if ((t & 63) == 0) wrow[t >> 6] = key;
            __syncthreads();
            unsigned long long k0 = wrow[0], k1 = wrow[1], k2 = wrow[2], k3 = wrow[3];
            if (k1 > k0) k0 = k1;
            if (k3 > k2) k2 = k3;
            if (k2 > k0) k0 = k2;
            winner = NPTS - 1 - (int)(unsigned)(k0 & 0xffffffffull);
            if (t == 0) fid[b * NOUT + i] = b * NPTS + winner;
        }
    } else {
        // ---------------- GEMM: h = relu(BN(x @ W^T + b)), bf16 MFMA ----------------
        const int bid = blockIdx.x - BATCH;
        const int bm = bid >> 2;           // 512 M-tiles of 128
        const int bn = bid & 3;            // 4 N-tiles of 128
        short* As = (short*)smem;          // [128][LDA] bf16
        short* Bs = As + 128 * LDA;        // [128][LDA] bf16 (W is [n][k] = B^T, perfect)

        const int lane = t & 63;
        const int wv = t >> 6;
        const int wm = wv >> 1, wn = wv & 1;   // 2x2 waves, 64x64 each
        const int quad = lane >> 4, l16 = lane & 15;
        const int m0 = bm * 128, n0 = bn * 128;

        f32x4 acc[4][4];
        const f32x4 zero = {0.0f, 0.0f, 0.0f, 0.0f};
#pragma unroll
        for (int a = 0; a < 4; ++a)
#pragma unroll
            for (int bb = 0; bb < 4; ++bb) acc[a][bb] = zero;

        const int srow = t >> 3;           // 0..31
        const int scol = (t & 7) << 2;     // 0,4,...,28

        for (int ks = 0; ks < 8; ++ks) {   // K = 256 in steps of 32
            const int k0 = ks * 32;
            __syncthreads();
#pragma unroll
            for (int it = 0; it < 4; ++it) {
                int row = srow + it * 32;
                float4 va = *(const float4*)(x + (size_t)(m0 + row) * CIN + k0 + scol);
                short4 pa = make_short4((short)f2bf_rne(va.x), (short)f2bf_rne(va.y),
                                        (short)f2bf_rne(va.z), (short)f2bf_rne(va.w));
                *(short4*)(As + row * LDA + scol) = pa;
                float4 vb = *(const float4*)(W + (size_t)(n0 + row) * CIN + k0 + scol);
                short4 pb2 = make_short4((short)f2bf_rne(vb.x), (short)f2bf_rne(vb.y),
                                         (short)f2bf_rne(vb.z), (short)f2bf_rne(vb.w));
                *(short4*)(Bs + row * LDA + scol) = pb2;
            }
            __syncthreads();
            bf16x8 af[4], bfr[4];
#pragma unroll
            for (int tm = 0; tm < 4; ++tm)
                af[tm] = *(const bf16x8*)(As + (wm * 64 + tm * 16 + l16) * LDA + quad * 8);
#pragma unroll
            for (int tn = 0; tn < 4; ++tn)
                bfr[tn] = *(const bf16x8*)(Bs + (wn * 64 + tn * 16 + l16) * LDA + quad * 8);
#pragma unroll
            for (int tm = 0; tm < 4; ++tm)
#pragma unroll
                for (int tn = 0; tn < 4; ++tn)
                    acc[tm][tn] = __builtin_amdgcn_mfma_f32_16x16x32_bf16(
                        af[tm], bfr[tn], acc[tm][tn], 0, 0, 0);
        }
        // epilogue: fold bias+BN, relu, store bf16
#pragma unroll
        for (int tn = 0; tn < 4; ++tn) {
            int c = n0 + wn * 64 + tn * 16 + l16;
            float sc = gamma[c] / sqrtf(rvar[c] + 1e-5f);
            float sh = (bias[c] - rmean[c]) * sc + beta[c];
#pragma unroll
            for (int tm = 0; tm < 4; ++tm) {
                int rbase = m0 + wm * 64 + tm * 16 + quad * 4;
#pragma unroll
                for (int r = 0; r < 4; ++r) {
                    float v = fmaxf(acc[tm][tn][r] * sc + sh, 0.0f);
                    h[(size_t)(rbase + r) * COUT + c] = f2bf_rne(v);
                }
            }
        }
    }
}

// one block per sampled point: gather K=16 rows of h, max over K, + p_out copy
extern "C" __global__ void __launch_bounds__(128)
gather_maxpool(const int* __restrict__ sid32, const float* __restrict__ p,
               const int* __restrict__ fid, const unsigned short* __restrict__ h,
               float* __restrict__ out)
{
    const int j = blockIdx.x;     // 0..16383
    const int t = threadIdx.x;
    __shared__ int rows[KNN];
    const int frow = fid[j];
    // sid_euc may land as int32 or int64 depending on JAX x64 config; int64 high
    // words of nonneg values < 2^31 are all zero -> sniff.
    bool is64 = (sid32[1] == 0) && (sid32[3] == 0) && (sid32[5] == 0);
    if (t < KNN) {
        long long e = (long long)frow * KNN + t;
        rows[t] = is64 ? sid32[e * 2] : sid32[e];
    }
    if (t < 3) out[(size_t)XOUT_ELEMS + (size_t)j * 3 + t] = p[(size_t)frow * 3 + t];
    __syncthreads();

    const int c4 = t << 2;
    float m0 = -3.4028235e38f, m1 = m0, m2 = m0, m3 = m0;
#pragma unroll
    for (int k = 0; k < KNN; ++k) {
        const ushort4 v = *(const ushort4*)(h + (size_t)rows[k] * COUT + c4);
        m0 = fmaxf(m0, bf2f(v.x));
        m1 = fmaxf(m1, bf2f(v.y));
        m2 = fmaxf(m2, bf2f(v.z));
        m3 = fmaxf(m3, bf2f(v.w));
    }
    *(float4*)(out + (size_t)j * COUT + c4) = make_float4(m0, m1, m2, m3);
}

extern "C" void kernel_launch(void* const* d_in, const int* in_sizes, int n_in,
                              void* d_out, int out_size, void* d_ws, size_t ws_size,
                              hipStream_t stream)
{
    const float* x     = (const float*)d_in[0];
    const float* p     = (const float*)d_in[1];
    const int*   sid   = (const int*)d_in[2];   // tid_euc (d_in[3]) unused by reference
    const float* W     = (const float*)d_in[4];
    const float* bias  = (const float*)d_in[5];
    const float* gamma = (const float*)d_in[6];
    const float* beta  = (const float*)d_in[7];
    const float* rmean = (const float*)d_in[8];
    const float* rvar  = (const float*)d_in[9];
    float* out = (float*)d_out;

    int* fid = (int*)d_ws;                                   // 16384 int32
    unsigned short* h = (unsigned short*)((char*)d_ws + 65536); // 65536x512 bf16 (67MB)

    const size_t lds = 3 * NPTS * 4 + 2 * 4 * 8;             // 49216 B (FPS needs most)
    hipLaunchKernelGGL(fused_fps_gemm, dim3(BATCH + 512 * 4), dim3(256), lds, stream,
                       x, p, W, bias, gamma, beta, rmean, rvar, fid, h);
    hipLaunchKernelGGL(gather_maxpool, dim3(BATCH * NOUT), dim3(128), 0, stream,
                       sid, p, fid, h, out);
}